// Round 1
// baseline (108.681 us; speedup 1.0000x reference)
//
#include <hip/hip_runtime.h>

#define TPB 256

// Fused: corner gather + trilinear interp + 64x64 projection.
// Block = 64 samples. Phase 1: wave w computes samples [w*16, w*16+16),
// lane = embed dim. Phase 2: 64x64x64 tile GEMM from LDS, 4x4 micro-tile
// per thread.
__global__ __launch_bounds__(TPB) void fused_embed_proj_kernel(
    const float* __restrict__ values,   // [K,64]
    const float* __restrict__ p,        // [N,3]
    const float* __restrict__ W,        // [64,64]
    const float* __restrict__ b,        // [64]
    const int*   __restrict__ feats,    // [V,8]
    const int*   __restrict__ vidx,     // [N]
    float* __restrict__ out,            // [N,64]
    int N)
{
    __shared__ float featS[64][65];   // [sample][dim], +1 pad
    __shared__ float Wlds[64][64];    // [d][d2], rows 256B -> float4-aligned

    const int t    = threadIdx.x;
    const int base = blockIdx.x * 64;

    // ---- stage W into LDS (4096 floats, 16 per thread as float4) ----
    {
        const float4* Wv = (const float4*)W;
        float4*       Wl = (float4*)&Wlds[0][0];
        #pragma unroll
        for (int i = 0; i < 4; ++i)
            Wl[t + i * TPB] = Wv[t + i * TPB];
    }

    const int lane = t & 63;
    const int wv   = t >> 6;   // wave id 0..3

    // ---- phase 1: trilinear-weighted gather -> featS ----
    #pragma unroll 2
    for (int i = 0; i < 16; ++i) {
        const int s = wv * 16 + i;
        const int n = base + s;
        if (n < N) {
            const int v = vidx[n];               // wave-uniform
            const int* fr = feats + (size_t)v * 8;
            const int c0 = fr[0], c1 = fr[1], c2 = fr[2], c3 = fr[3];
            const int c4 = fr[4], c5 = fr[5], c6 = fr[6], c7 = fr[7];

            const float px = p[n * 3 + 0];
            const float py = p[n * 3 + 1];
            const float pz = p[n * 3 + 2];
            const float ox = 1.0f - px, oy = 1.0f - py, oz = 1.0f - pz;
            // corner order: [1,1,1],[1,1,0],[1,0,1],[0,1,1],[1,0,0],[0,1,0],[0,0,1],[0,0,0]
            const float w0 = px * py * pz;
            const float w1 = px * py * oz;
            const float w2 = px * oy * pz;
            const float w3 = ox * py * pz;
            const float w4 = px * oy * oz;
            const float w5 = ox * py * oz;
            const float w6 = ox * oy * pz;
            const float w7 = ox * oy * oz;

            // 8 coalesced 256B row reads (lane = dim)
            const float v0 = values[(size_t)c0 * 64 + lane];
            const float v1 = values[(size_t)c1 * 64 + lane];
            const float v2 = values[(size_t)c2 * 64 + lane];
            const float v3 = values[(size_t)c3 * 64 + lane];
            const float v4 = values[(size_t)c4 * 64 + lane];
            const float v5 = values[(size_t)c5 * 64 + lane];
            const float v6 = values[(size_t)c6 * 64 + lane];
            const float v7 = values[(size_t)c7 * 64 + lane];

            float acc = w0 * v0;
            acc = fmaf(w1, v1, acc);
            acc = fmaf(w2, v2, acc);
            acc = fmaf(w3, v3, acc);
            acc = fmaf(w4, v4, acc);
            acc = fmaf(w5, v5, acc);
            acc = fmaf(w6, v6, acc);
            acc = fmaf(w7, v7, acc);
            featS[s][lane] = acc;
        }
    }
    __syncthreads();

    // ---- phase 2: featS[64x64] @ Wlds[64x64] + b ----
    const int tx = t & 15;   // out-dim group: dims 4*tx .. 4*tx+3
    const int ty = t >> 4;   // sample group : samples 4*ty .. 4*ty+3

    float acc[4][4];
    {
        const float4 bb = ((const float4*)b)[tx];
        #pragma unroll
        for (int j = 0; j < 4; ++j) {
            acc[j][0] = bb.x; acc[j][1] = bb.y; acc[j][2] = bb.z; acc[j][3] = bb.w;
        }
    }

    #pragma unroll 4
    for (int d = 0; d < 64; ++d) {
        const float a0 = featS[4 * ty + 0][d];   // broadcast reads
        const float a1 = featS[4 * ty + 1][d];
        const float a2 = featS[4 * ty + 2][d];
        const float a3 = featS[4 * ty + 3][d];
        const float4 wr = *(const float4*)&Wlds[d][4 * tx];  // 2-way = free
        acc[0][0] = fmaf(a0, wr.x, acc[0][0]);
        acc[0][1] = fmaf(a0, wr.y, acc[0][1]);
        acc[0][2] = fmaf(a0, wr.z, acc[0][2]);
        acc[0][3] = fmaf(a0, wr.w, acc[0][3]);
        acc[1][0] = fmaf(a1, wr.x, acc[1][0]);
        acc[1][1] = fmaf(a1, wr.y, acc[1][1]);
        acc[1][2] = fmaf(a1, wr.z, acc[1][2]);
        acc[1][3] = fmaf(a1, wr.w, acc[1][3]);
        acc[2][0] = fmaf(a2, wr.x, acc[2][0]);
        acc[2][1] = fmaf(a2, wr.y, acc[2][1]);
        acc[2][2] = fmaf(a2, wr.z, acc[2][2]);
        acc[2][3] = fmaf(a2, wr.w, acc[2][3]);
        acc[3][0] = fmaf(a3, wr.x, acc[3][0]);
        acc[3][1] = fmaf(a3, wr.y, acc[3][1]);
        acc[3][2] = fmaf(a3, wr.z, acc[3][2]);
        acc[3][3] = fmaf(a3, wr.w, acc[3][3]);
    }

    // ---- store: float4 per sample-row ----
    #pragma unroll
    for (int j = 0; j < 4; ++j) {
        const int n = base + 4 * ty + j;
        if (n < N) {
            float4 o;
            o.x = acc[j][0]; o.y = acc[j][1]; o.z = acc[j][2]; o.w = acc[j][3];
            *(float4*)&out[(size_t)n * 64 + 4 * tx] = o;
        }
    }
}

extern "C" void kernel_launch(void* const* d_in, const int* in_sizes, int n_in,
                              void* d_out, int out_size, void* d_ws, size_t ws_size,
                              hipStream_t stream) {
    const float* values = (const float*)d_in[0];
    const float* p      = (const float*)d_in[1];
    const float* W      = (const float*)d_in[2];
    const float* b      = (const float*)d_in[3];
    const int*   feats  = (const int*)d_in[4];
    const int*   vidx   = (const int*)d_in[5];
    float* out = (float*)d_out;

    const int N = in_sizes[5];           // number of samples
    const int nblocks = (N + 63) / 64;

    fused_embed_proj_kernel<<<nblocks, TPB, 0, stream>>>(
        values, p, W, b, feats, vidx, out, N);
}

// Round 2
// 87.010 us; speedup vs baseline: 1.2491x; 1.2491x over previous
//
#include <hip/hip_runtime.h>

#define TPB 256

// Fused: corner gather + trilinear interp + 64x64 projection.
// Block = 64 samples.
// Phase 1: thread t owns (sample s = (t>>4) + 16i, dim-group g = t&15).
//          All 32 corner indices + weights precomputed, then 32 independent
//          float4 gathers (1 KB per wave instruction).
// Phase 2: 64x64x64 tile GEMM from LDS, 4x4 micro-tile per thread.
__global__ __launch_bounds__(TPB) void fused_embed_proj_kernel(
    const float* __restrict__ values,   // [K,64]
    const float* __restrict__ p,        // [N,3]
    const float* __restrict__ W,        // [64,64]
    const float* __restrict__ b,        // [64]
    const int*   __restrict__ feats,    // [V,8]
    const int*   __restrict__ vidx,     // [N]
    float* __restrict__ out,            // [N,64]
    int N)
{
    __shared__ float featS[64][68];   // stride 68 floats = 272 B (16B-aligned rows)
    __shared__ float Wlds[64][64];

    const int t    = threadIdx.x;
    const int base = blockIdx.x * 64;

    // ---- stage W into LDS (4096 floats, float4 per thread x4) ----
    {
        const float4* Wv = (const float4*)W;
        float4*       Wl = (float4*)&Wlds[0][0];
        #pragma unroll
        for (int i = 0; i < 4; ++i)
            Wl[t + i * TPB] = Wv[t + i * TPB];
    }

    const int g  = t & 15;    // dim group: dims 4g..4g+3
    const int sb = t >> 4;    // sample sub-index 0..15

    // ---- phase 1a: precompute all corner indices + weights (independent chains) ----
    int   cidx[4][8];
    float wgt[4][8];
    #pragma unroll
    for (int i = 0; i < 4; ++i) {
        const int s  = sb + 16 * i;
        int n        = base + s;
        if (n >= N) n = N - 1;            // clamp: garbage feat rows are never stored

        const int v  = vidx[n];
        const int4 f0 = *(const int4*)&feats[(size_t)v * 8];
        const int4 f1 = *(const int4*)&feats[(size_t)v * 8 + 4];
        cidx[i][0] = f0.x; cidx[i][1] = f0.y; cidx[i][2] = f0.z; cidx[i][3] = f0.w;
        cidx[i][4] = f1.x; cidx[i][5] = f1.y; cidx[i][6] = f1.z; cidx[i][7] = f1.w;

        const float px = p[n * 3 + 0];
        const float py = p[n * 3 + 1];
        const float pz = p[n * 3 + 2];
        const float ox = 1.0f - px, oy = 1.0f - py, oz = 1.0f - pz;
        // corner order: [1,1,1],[1,1,0],[1,0,1],[0,1,1],[1,0,0],[0,1,0],[0,0,1],[0,0,0]
        wgt[i][0] = px * py * pz;
        wgt[i][1] = px * py * oz;
        wgt[i][2] = px * oy * pz;
        wgt[i][3] = ox * py * pz;
        wgt[i][4] = px * oy * oz;
        wgt[i][5] = ox * py * oz;
        wgt[i][6] = ox * oy * pz;
        wgt[i][7] = ox * oy * oz;
    }

    // ---- phase 1b: 32 independent float4 gathers, weighted accumulate ----
    float4 facc[4];
    #pragma unroll
    for (int i = 0; i < 4; ++i) {
        float4 acc; acc.x = 0.f; acc.y = 0.f; acc.z = 0.f; acc.w = 0.f;
        #pragma unroll
        for (int c = 0; c < 8; ++c) {
            const float4 val = *(const float4*)&values[(size_t)cidx[i][c] * 64 + 4 * g];
            const float  w   = wgt[i][c];
            acc.x = fmaf(w, val.x, acc.x);
            acc.y = fmaf(w, val.y, acc.y);
            acc.z = fmaf(w, val.z, acc.z);
            acc.w = fmaf(w, val.w, acc.w);
        }
        facc[i] = acc;
    }
    #pragma unroll
    for (int i = 0; i < 4; ++i) {
        const int s = sb + 16 * i;
        *(float4*)&featS[s][4 * g] = facc[i];
    }
    __syncthreads();

    // ---- phase 2: featS[64x64] @ Wlds[64x64] + b ----
    const int tx = t & 15;   // out-dim group: dims 4*tx .. 4*tx+3
    const int ty = t >> 4;   // sample group : samples 4*ty .. 4*ty+3

    float acc[4][4];
    {
        const float4 bb = ((const float4*)b)[tx];
        #pragma unroll
        for (int j = 0; j < 4; ++j) {
            acc[j][0] = bb.x; acc[j][1] = bb.y; acc[j][2] = bb.z; acc[j][3] = bb.w;
        }
    }

    #pragma unroll 4
    for (int d = 0; d < 64; ++d) {
        const float a0 = featS[4 * ty + 0][d];   // broadcast reads
        const float a1 = featS[4 * ty + 1][d];
        const float a2 = featS[4 * ty + 2][d];
        const float a3 = featS[4 * ty + 3][d];
        const float4 wr = *(const float4*)&Wlds[d][4 * tx];
        acc[0][0] = fmaf(a0, wr.x, acc[0][0]);
        acc[0][1] = fmaf(a0, wr.y, acc[0][1]);
        acc[0][2] = fmaf(a0, wr.z, acc[0][2]);
        acc[0][3] = fmaf(a0, wr.w, acc[0][3]);
        acc[1][0] = fmaf(a1, wr.x, acc[1][0]);
        acc[1][1] = fmaf(a1, wr.y, acc[1][1]);
        acc[1][2] = fmaf(a1, wr.z, acc[1][2]);
        acc[1][3] = fmaf(a1, wr.w, acc[1][3]);
        acc[2][0] = fmaf(a2, wr.x, acc[2][0]);
        acc[2][1] = fmaf(a2, wr.y, acc[2][1]);
        acc[2][2] = fmaf(a2, wr.z, acc[2][2]);
        acc[2][3] = fmaf(a2, wr.w, acc[2][3]);
        acc[3][0] = fmaf(a3, wr.x, acc[3][0]);
        acc[3][1] = fmaf(a3, wr.y, acc[3][1]);
        acc[3][2] = fmaf(a3, wr.z, acc[3][2]);
        acc[3][3] = fmaf(a3, wr.w, acc[3][3]);
    }

    // ---- store: float4 per sample-row ----
    #pragma unroll
    for (int j = 0; j < 4; ++j) {
        const int n = base + 4 * ty + j;
        if (n < N) {
            float4 o;
            o.x = acc[j][0]; o.y = acc[j][1]; o.z = acc[j][2]; o.w = acc[j][3];
            *(float4*)&out[(size_t)n * 64 + 4 * tx] = o;
        }
    }
}

extern "C" void kernel_launch(void* const* d_in, const int* in_sizes, int n_in,
                              void* d_out, int out_size, void* d_ws, size_t ws_size,
                              hipStream_t stream) {
    const float* values = (const float*)d_in[0];
    const float* p      = (const float*)d_in[1];
    const float* W      = (const float*)d_in[2];
    const float* b      = (const float*)d_in[3];
    const int*   feats  = (const int*)d_in[4];
    const int*   vidx   = (const int*)d_in[5];
    float* out = (float*)d_out;

    const int N = in_sizes[5];
    const int nblocks = (N + 63) / 64;

    fused_embed_proj_kernel<<<nblocks, TPB, 0, stream>>>(
        values, p, W, b, feats, vidx, out, N);
}

// Round 3
// 83.986 us; speedup vs baseline: 1.2940x; 1.0360x over previous
//
#include <hip/hip_runtime.h>

#define TPB 256

__device__ __forceinline__ unsigned pack_bf16_rne(float lo, float hi) {
    union { float f; unsigned u; } a, b;
    a.f = lo; b.f = hi;
    unsigned ua = (a.u + 0x7fffu + ((a.u >> 16) & 1u)) >> 16;
    unsigned ub = (b.u + 0x7fffu + ((b.u >> 16) & 1u)) >> 16;
    return ua | (ub << 16);
}
__device__ __forceinline__ float bf_lo(unsigned u) {
    union { unsigned i; float f; } c; c.i = u << 16; return c.f;
}
__device__ __forceinline__ float bf_hi(unsigned u) {
    union { unsigned i; float f; } c; c.i = u & 0xffff0000u; return c.f;
}

// ---- values fp32 [K*64] -> bf16 packed [K*32 uints], 8 elems/thread ----
__global__ __launch_bounds__(TPB) void cvt_values_bf16(
    const float4* __restrict__ src, uint4* __restrict__ dst, int n8)
{
    int i = blockIdx.x * TPB + threadIdx.x;
    if (i < n8) {
        const float4 a = src[2 * i];
        const float4 b = src[2 * i + 1];
        uint4 o;
        o.x = pack_bf16_rne(a.x, a.y);
        o.y = pack_bf16_rne(a.z, a.w);
        o.z = pack_bf16_rne(b.x, b.y);
        o.w = pack_bf16_rne(b.z, b.w);
        dst[i] = o;
    }
}

// ---- main fused kernel, bf16 gather path ----
// Block = 64 samples, 256 threads, LDS = featS only (17.4 KB).
// Phase 1: thread t owns (sample slot si = t>>3 (+32), dim octet g8 = t&7).
//          Gather = uint4 (8 bf16) per corner row; 8 lanes cover a 128B row.
// Phase 2: 64x64x64 GEMM, feat from LDS, W float4 straight from global (L1-hot).
__global__ __launch_bounds__(TPB) void fused_embed_proj_bf16(
    const unsigned* __restrict__ valbf,  // [K,32] packed bf16 rows (128 B/row)
    const float* __restrict__ p,         // [N,3]
    const float* __restrict__ W,         // [64,64]
    const float* __restrict__ b,         // [64]
    const int*   __restrict__ feats,     // [V,8]
    const int*   __restrict__ vidx,      // [N]
    float* __restrict__ out,             // [N,64]
    int N)
{
    __shared__ float featS[64][68];

    const int t    = threadIdx.x;
    const int base = blockIdx.x * 64;
    const int g8   = t & 7;    // dims 8*g8 .. 8*g8+7
    const int si   = t >> 3;   // 0..31

    // ---- phase 1a: precompute corner indices + weights for both samples ----
    int   cidx[2][8];
    float wgt[2][8];
    #pragma unroll
    for (int i = 0; i < 2; ++i) {
        const int s = si + 32 * i;
        int n = base + s;
        if (n >= N) n = N - 1;              // clamped lanes never store

        const int v = vidx[n];
        const int4 f0 = *(const int4*)&feats[(size_t)v * 8];
        const int4 f1 = *(const int4*)&feats[(size_t)v * 8 + 4];
        cidx[i][0] = f0.x; cidx[i][1] = f0.y; cidx[i][2] = f0.z; cidx[i][3] = f0.w;
        cidx[i][4] = f1.x; cidx[i][5] = f1.y; cidx[i][6] = f1.z; cidx[i][7] = f1.w;

        const float px = p[n * 3 + 0];
        const float py = p[n * 3 + 1];
        const float pz = p[n * 3 + 2];
        const float ox = 1.0f - px, oy = 1.0f - py, oz = 1.0f - pz;
        // corner order: [1,1,1],[1,1,0],[1,0,1],[0,1,1],[1,0,0],[0,1,0],[0,0,1],[0,0,0]
        wgt[i][0] = px * py * pz;
        wgt[i][1] = px * py * oz;
        wgt[i][2] = px * oy * pz;
        wgt[i][3] = ox * py * pz;
        wgt[i][4] = px * oy * oz;
        wgt[i][5] = ox * py * oz;
        wgt[i][6] = ox * oy * pz;
        wgt[i][7] = ox * oy * oz;
    }

    // ---- phase 1b: 16 independent uint4 (8x bf16) gathers, fp32 accumulate ----
    #pragma unroll
    for (int i = 0; i < 2; ++i) {
        float a0 = 0.f, a1 = 0.f, a2 = 0.f, a3 = 0.f;
        float a4 = 0.f, a5 = 0.f, a6 = 0.f, a7 = 0.f;
        #pragma unroll
        for (int c = 0; c < 8; ++c) {
            const uint4 q = *(const uint4*)&valbf[(size_t)cidx[i][c] * 32 + 4 * g8];
            const float w = wgt[i][c];
            a0 = fmaf(w, bf_lo(q.x), a0);
            a1 = fmaf(w, bf_hi(q.x), a1);
            a2 = fmaf(w, bf_lo(q.y), a2);
            a3 = fmaf(w, bf_hi(q.y), a3);
            a4 = fmaf(w, bf_lo(q.z), a4);
            a5 = fmaf(w, bf_hi(q.z), a5);
            a6 = fmaf(w, bf_lo(q.w), a6);
            a7 = fmaf(w, bf_hi(q.w), a7);
        }
        const int s = si + 32 * i;
        float4 lo; lo.x = a0; lo.y = a1; lo.z = a2; lo.w = a3;
        float4 hi; hi.x = a4; hi.y = a5; hi.z = a6; hi.w = a7;
        *(float4*)&featS[s][8 * g8]     = lo;
        *(float4*)&featS[s][8 * g8 + 4] = hi;
    }
    __syncthreads();

    // ---- phase 2: featS[64x64] @ W[64x64] + b (W via L1) ----
    const int tx = t & 15;   // out dims 4*tx .. 4*tx+3
    const int ty = t >> 4;   // samples 4*ty .. 4*ty+3

    float acc[4][4];
    {
        const float4 bb = ((const float4*)b)[tx];
        #pragma unroll
        for (int j = 0; j < 4; ++j) {
            acc[j][0] = bb.x; acc[j][1] = bb.y; acc[j][2] = bb.z; acc[j][3] = bb.w;
        }
    }

    #pragma unroll 4
    for (int d = 0; d < 64; ++d) {
        const float a0 = featS[4 * ty + 0][d];
        const float a1 = featS[4 * ty + 1][d];
        const float a2 = featS[4 * ty + 2][d];
        const float a3 = featS[4 * ty + 3][d];
        const float4 wr = *(const float4*)&W[(size_t)d * 64 + 4 * tx];
        acc[0][0] = fmaf(a0, wr.x, acc[0][0]);
        acc[0][1] = fmaf(a0, wr.y, acc[0][1]);
        acc[0][2] = fmaf(a0, wr.z, acc[0][2]);
        acc[0][3] = fmaf(a0, wr.w, acc[0][3]);
        acc[1][0] = fmaf(a1, wr.x, acc[1][0]);
        acc[1][1] = fmaf(a1, wr.y, acc[1][1]);
        acc[1][2] = fmaf(a1, wr.z, acc[1][2]);
        acc[1][3] = fmaf(a1, wr.w, acc[1][3]);
        acc[2][0] = fmaf(a2, wr.x, acc[2][0]);
        acc[2][1] = fmaf(a2, wr.y, acc[2][1]);
        acc[2][2] = fmaf(a2, wr.z, acc[2][2]);
        acc[2][3] = fmaf(a2, wr.w, acc[2][3]);
        acc[3][0] = fmaf(a3, wr.x, acc[3][0]);
        acc[3][1] = fmaf(a3, wr.y, acc[3][1]);
        acc[3][2] = fmaf(a3, wr.z, acc[3][2]);
        acc[3][3] = fmaf(a3, wr.w, acc[3][3]);
    }

    #pragma unroll
    for (int j = 0; j < 4; ++j) {
        const int n = base + 4 * ty + j;
        if (n < N) {
            float4 o;
            o.x = acc[j][0]; o.y = acc[j][1]; o.z = acc[j][2]; o.w = acc[j][3];
            *(float4*)&out[(size_t)n * 64 + 4 * tx] = o;
        }
    }
}

// ---- fallback: proven round-2 fp32 kernel (used only if ws too small) ----
__global__ __launch_bounds__(TPB) void fused_embed_proj_fp32(
    const float* __restrict__ values, const float* __restrict__ p,
    const float* __restrict__ W, const float* __restrict__ b,
    const int* __restrict__ feats, const int* __restrict__ vidx,
    float* __restrict__ out, int N)
{
    __shared__ float featS[64][68];
    __shared__ float Wlds[64][64];

    const int t    = threadIdx.x;
    const int base = blockIdx.x * 64;
    {
        const float4* Wv = (const float4*)W;
        float4*       Wl = (float4*)&Wlds[0][0];
        #pragma unroll
        for (int i = 0; i < 4; ++i) Wl[t + i * TPB] = Wv[t + i * TPB];
    }
    const int g  = t & 15;
    const int sb = t >> 4;

    int   cidx[4][8];
    float wgt[4][8];
    #pragma unroll
    for (int i = 0; i < 4; ++i) {
        const int s = sb + 16 * i;
        int n = base + s;
        if (n >= N) n = N - 1;
        const int v = vidx[n];
        const int4 f0 = *(const int4*)&feats[(size_t)v * 8];
        const int4 f1 = *(const int4*)&feats[(size_t)v * 8 + 4];
        cidx[i][0] = f0.x; cidx[i][1] = f0.y; cidx[i][2] = f0.z; cidx[i][3] = f0.w;
        cidx[i][4] = f1.x; cidx[i][5] = f1.y; cidx[i][6] = f1.z; cidx[i][7] = f1.w;
        const float px = p[n * 3], py = p[n * 3 + 1], pz = p[n * 3 + 2];
        const float ox = 1.f - px, oy = 1.f - py, oz = 1.f - pz;
        wgt[i][0] = px * py * pz; wgt[i][1] = px * py * oz;
        wgt[i][2] = px * oy * pz; wgt[i][3] = ox * py * pz;
        wgt[i][4] = px * oy * oz; wgt[i][5] = ox * py * oz;
        wgt[i][6] = ox * oy * pz; wgt[i][7] = ox * oy * oz;
    }
    #pragma unroll
    for (int i = 0; i < 4; ++i) {
        float4 acc; acc.x = acc.y = acc.z = acc.w = 0.f;
        #pragma unroll
        for (int c = 0; c < 8; ++c) {
            const float4 val = *(const float4*)&values[(size_t)cidx[i][c] * 64 + 4 * g];
            const float w = wgt[i][c];
            acc.x = fmaf(w, val.x, acc.x); acc.y = fmaf(w, val.y, acc.y);
            acc.z = fmaf(w, val.z, acc.z); acc.w = fmaf(w, val.w, acc.w);
        }
        *(float4*)&featS[sb + 16 * i][4 * g] = acc;
    }
    __syncthreads();

    const int tx = t & 15, ty = t >> 4;
    float acc[4][4];
    {
        const float4 bb = ((const float4*)b)[tx];
        #pragma unroll
        for (int j = 0; j < 4; ++j) {
            acc[j][0] = bb.x; acc[j][1] = bb.y; acc[j][2] = bb.z; acc[j][3] = bb.w;
        }
    }
    #pragma unroll 4
    for (int d = 0; d < 64; ++d) {
        const float a0 = featS[4 * ty + 0][d];
        const float a1 = featS[4 * ty + 1][d];
        const float a2 = featS[4 * ty + 2][d];
        const float a3 = featS[4 * ty + 3][d];
        const float4 wr = *(const float4*)&Wlds[d][4 * tx];
        acc[0][0] = fmaf(a0, wr.x, acc[0][0]); acc[0][1] = fmaf(a0, wr.y, acc[0][1]);
        acc[0][2] = fmaf(a0, wr.z, acc[0][2]); acc[0][3] = fmaf(a0, wr.w, acc[0][3]);
        acc[1][0] = fmaf(a1, wr.x, acc[1][0]); acc[1][1] = fmaf(a1, wr.y, acc[1][1]);
        acc[1][2] = fmaf(a1, wr.z, acc[1][2]); acc[1][3] = fmaf(a1, wr.w, acc[1][3]);
        acc[2][0] = fmaf(a2, wr.x, acc[2][0]); acc[2][1] = fmaf(a2, wr.y, acc[2][1]);
        acc[2][2] = fmaf(a2, wr.z, acc[2][2]); acc[2][3] = fmaf(a2, wr.w, acc[2][3]);
        acc[3][0] = fmaf(a3, wr.x, acc[3][0]); acc[3][1] = fmaf(a3, wr.y, acc[3][1]);
        acc[3][2] = fmaf(a3, wr.z, acc[3][2]); acc[3][3] = fmaf(a3, wr.w, acc[3][3]);
    }
    #pragma unroll
    for (int j = 0; j < 4; ++j) {
        const int n = base + 4 * ty + j;
        if (n < N) {
            float4 o; o.x = acc[j][0]; o.y = acc[j][1]; o.z = acc[j][2]; o.w = acc[j][3];
            *(float4*)&out[(size_t)n * 64 + 4 * tx] = o;
        }
    }
}

extern "C" void kernel_launch(void* const* d_in, const int* in_sizes, int n_in,
                              void* d_out, int out_size, void* d_ws, size_t ws_size,
                              hipStream_t stream) {
    const float* values = (const float*)d_in[0];
    const float* p      = (const float*)d_in[1];
    const float* W      = (const float*)d_in[2];
    const float* b      = (const float*)d_in[3];
    const int*   feats  = (const int*)d_in[4];
    const int*   vidx   = (const int*)d_in[5];
    float* out = (float*)d_out;

    const int N  = in_sizes[5];
    const int KD = in_sizes[0];            // K * 64
    const int nblocks = (N + 63) / 64;

    const size_t need = (size_t)KD * 2;    // bf16 table bytes
    if (ws_size >= need) {
        unsigned* valbf = (unsigned*)d_ws;
        const int n8 = KD / 8;
        cvt_values_bf16<<<(n8 + TPB - 1) / TPB, TPB, 0, stream>>>(
            (const float4*)values, (uint4*)valbf, n8);
        fused_embed_proj_bf16<<<nblocks, TPB, 0, stream>>>(
            valbf, p, W, b, feats, vidx, out, N);
    } else {
        fused_embed_proj_fp32<<<nblocks, TPB, 0, stream>>>(
            values, p, W, b, feats, vidx, out, N);
    }
}

// Round 4
// 71.386 us; speedup vs baseline: 1.5224x; 1.1765x over previous
//
#include <hip/hip_runtime.h>

#define TPB 256

typedef __attribute__((ext_vector_type(8))) short bf16x8;
typedef __attribute__((ext_vector_type(4))) float f32x4;

__device__ __forceinline__ unsigned pack_bf16_rne(float lo, float hi) {
    union { float f; unsigned u; } a, b;
    a.f = lo; b.f = hi;
    unsigned ua = (a.u + 0x7fffu + ((a.u >> 16) & 1u)) >> 16;
    unsigned ub = (b.u + 0x7fffu + ((b.u >> 16) & 1u)) >> 16;
    return ua | (ub << 16);
}
__device__ __forceinline__ float bf_lo(unsigned u) {
    union { unsigned i; float f; } c; c.i = u << 16; return c.f;
}
__device__ __forceinline__ float bf_hi(unsigned u) {
    union { unsigned i; float f; } c; c.i = u & 0xffff0000u; return c.f;
}

// ---- values fp32 [K*64] -> bf16 packed [K*32 uints] ----
__global__ __launch_bounds__(TPB) void cvt_values_bf16(
    const float4* __restrict__ src, uint4* __restrict__ dst, int n8)
{
    int i = blockIdx.x * TPB + threadIdx.x;
    if (i < n8) {
        const float4 a = src[2 * i];
        const float4 b = src[2 * i + 1];
        uint4 o;
        o.x = pack_bf16_rne(a.x, a.y);
        o.y = pack_bf16_rne(a.z, a.w);
        o.z = pack_bf16_rne(b.x, b.y);
        o.w = pack_bf16_rne(b.z, b.w);
        dst[i] = o;
    }
}

// ---- W [64,64] fp32 -> bf16 MFMA B-fragments ----
// frag f = ct*2 + kf (ct: col-tile 0..3, kf: k-half 0..1), lane l:
//   element j (0..7) = W[kf*32 + 8*(l>>4) + j][ct*16 + (l&15)]
// stored as uint4 (8 bf16) at wfrag[f*64 + l].
__global__ void cvt_w_frag(const float* __restrict__ W, uint4* __restrict__ wfrag)
{
    const int t = threadIdx.x;
    for (int e = t; e < 512; e += TPB) {
        const int l  = e & 63;
        const int f  = e >> 6;
        const int ct = f >> 1;
        const int kf = f & 1;
        const int col = ct * 16 + (l & 15);
        const int k0  = kf * 32 + 8 * (l >> 4);
        uint4 o;
        o.x = pack_bf16_rne(W[(k0 + 0) * 64 + col], W[(k0 + 1) * 64 + col]);
        o.y = pack_bf16_rne(W[(k0 + 2) * 64 + col], W[(k0 + 3) * 64 + col]);
        o.z = pack_bf16_rne(W[(k0 + 4) * 64 + col], W[(k0 + 5) * 64 + col]);
        o.w = pack_bf16_rne(W[(k0 + 6) * 64 + col], W[(k0 + 7) * 64 + col]);
        wfrag[e] = o;
    }
}

// ---- main fused kernel ----
// Block = 64 samples, 256 threads (4 waves).
// Phase 1: thread t owns (sample si = t>>3 (+32), dim octet g8 = t&7).
//          uint4 (8 bf16) gathers; fp32 accumulate; swizzled featS write:
//          physical 8-float block = (g8 + s) & 7  (row stride 68 floats).
// Phase 2: wave w computes samples 16w..16w+15 x all 64 out dims via
//          8x mfma_f32_16x16x32_bf16 with precomputed W fragments.
__global__ __launch_bounds__(TPB) void fused_embed_proj_mfma(
    const unsigned* __restrict__ valbf,  // [K,32] packed bf16 rows (128 B/row)
    const float* __restrict__ p,         // [N,3]
    const uint4* __restrict__ wfrag,     // [8][64] B-fragments
    const float* __restrict__ b,         // [64]
    const int*   __restrict__ feats,     // [V,8]
    const int*   __restrict__ vidx,      // [N]
    float* __restrict__ out,             // [N,64]
    int N)
{
    __shared__ float featS[64][68];

    const int t    = threadIdx.x;
    const int base = blockIdx.x * 64;
    const int g8   = t & 7;    // dim block: dims 8*g8 .. 8*g8+7
    const int si   = t >> 3;   // 0..31

    // ---- phase 1a: corner indices + weights for both owned samples ----
    int   cidx[2][8];
    float wgt[2][8];
    #pragma unroll
    for (int i = 0; i < 2; ++i) {
        const int s = si + 32 * i;
        int n = base + s;
        if (n >= N) n = N - 1;             // clamped lanes never store

        const int v = vidx[n];
        const int4 f0 = *(const int4*)&feats[(size_t)v * 8];
        const int4 f1 = *(const int4*)&feats[(size_t)v * 8 + 4];
        cidx[i][0] = f0.x; cidx[i][1] = f0.y; cidx[i][2] = f0.z; cidx[i][3] = f0.w;
        cidx[i][4] = f1.x; cidx[i][5] = f1.y; cidx[i][6] = f1.z; cidx[i][7] = f1.w;

        const float px = p[n * 3 + 0];
        const float py = p[n * 3 + 1];
        const float pz = p[n * 3 + 2];
        const float ox = 1.0f - px, oy = 1.0f - py, oz = 1.0f - pz;
        // corner order: [1,1,1],[1,1,0],[1,0,1],[0,1,1],[1,0,0],[0,1,0],[0,0,1],[0,0,0]
        wgt[i][0] = px * py * pz;
        wgt[i][1] = px * py * oz;
        wgt[i][2] = px * oy * pz;
        wgt[i][3] = ox * py * pz;
        wgt[i][4] = px * oy * oz;
        wgt[i][5] = ox * py * oz;
        wgt[i][6] = ox * oy * pz;
        wgt[i][7] = ox * oy * oz;
    }

    // ---- phase 1b: 16 independent uint4 gathers, fp32 accumulate ----
    #pragma unroll
    for (int i = 0; i < 2; ++i) {
        float a0 = 0.f, a1 = 0.f, a2 = 0.f, a3 = 0.f;
        float a4 = 0.f, a5 = 0.f, a6 = 0.f, a7 = 0.f;
        #pragma unroll
        for (int c = 0; c < 8; ++c) {
            const uint4 q = *(const uint4*)&valbf[(size_t)cidx[i][c] * 32 + 4 * g8];
            const float w = wgt[i][c];
            a0 = fmaf(w, bf_lo(q.x), a0);
            a1 = fmaf(w, bf_hi(q.x), a1);
            a2 = fmaf(w, bf_lo(q.y), a2);
            a3 = fmaf(w, bf_hi(q.y), a3);
            a4 = fmaf(w, bf_lo(q.z), a4);
            a5 = fmaf(w, bf_hi(q.z), a5);
            a6 = fmaf(w, bf_lo(q.w), a6);
            a7 = fmaf(w, bf_hi(q.w), a7);
        }
        const int s  = si + 32 * i;
        const int pc = ((g8 + s) & 7) << 3;   // swizzled physical 8-float block
        float4 lo; lo.x = a0; lo.y = a1; lo.z = a2; lo.w = a3;
        float4 hi; hi.x = a4; hi.y = a5; hi.z = a6; hi.w = a7;
        *(float4*)&featS[s][pc]     = lo;
        *(float4*)&featS[s][pc + 4] = hi;
    }

    // ---- W fragments + bias (independent of featS; overlap barrier) ----
    const int l = t & 63;
    const int w = t >> 6;
    uint4 wf[8];
    #pragma unroll
    for (int f = 0; f < 8; ++f) wf[f] = wfrag[f * 64 + l];
    float bias[4];
    #pragma unroll
    for (int ct = 0; ct < 4; ++ct) bias[ct] = b[ct * 16 + (l & 15)];

    __syncthreads();

    // ---- phase 2: MFMA projection ----
    const int arow = 16 * w + (l & 15);   // sample row within block
    const int kg   = l >> 4;              // k-group 0..3

    // A-fragments for kf=0,1: element j = featS[arow][kf*32 + 8*kg + j]
    bf16x8 afrag[2];
    #pragma unroll
    for (int kf = 0; kf < 2; ++kf) {
        const int bk = 4 * kf + kg;                    // logical 8-block
        const int pc = ((bk + arow) & 7) << 3;         // physical (same swizzle)
        const float4 x0 = *(const float4*)&featS[arow][pc];
        const float4 x1 = *(const float4*)&featS[arow][pc + 4];
        union { unsigned u[4]; bf16x8 v; } cvt;
        cvt.u[0] = pack_bf16_rne(x0.x, x0.y);
        cvt.u[1] = pack_bf16_rne(x0.z, x0.w);
        cvt.u[2] = pack_bf16_rne(x1.x, x1.y);
        cvt.u[3] = pack_bf16_rne(x1.z, x1.w);
        afrag[kf] = cvt.v;
    }

    #pragma unroll
    for (int ct = 0; ct < 4; ++ct) {
        f32x4 acc;
        acc[0] = bias[ct]; acc[1] = bias[ct]; acc[2] = bias[ct]; acc[3] = bias[ct];
        union { uint4 u; bf16x8 v; } b0, b1;
        b0.u = wf[ct * 2 + 0];
        b1.u = wf[ct * 2 + 1];
        acc = __builtin_amdgcn_mfma_f32_16x16x32_bf16(afrag[0], b0.v, acc, 0, 0, 0);
        acc = __builtin_amdgcn_mfma_f32_16x16x32_bf16(afrag[1], b1.v, acc, 0, 0, 0);

        const int col = ct * 16 + (l & 15);
        #pragma unroll
        for (int r = 0; r < 4; ++r) {
            const int n = base + 16 * w + kg * 4 + r;  // C row = (l>>4)*4 + r
            if (n < N) out[(size_t)n * 64 + col] = acc[r];
        }
    }
}

// ---- fallback: proven round-2 fp32 kernel (used only if ws too small) ----
__global__ __launch_bounds__(TPB) void fused_embed_proj_fp32(
    const float* __restrict__ values, const float* __restrict__ p,
    const float* __restrict__ W, const float* __restrict__ b,
    const int* __restrict__ feats, const int* __restrict__ vidx,
    float* __restrict__ out, int N)
{
    __shared__ float featS[64][68];
    __shared__ float Wlds[64][64];

    const int t    = threadIdx.x;
    const int base = blockIdx.x * 64;
    {
        const float4* Wv = (const float4*)W;
        float4*       Wl = (float4*)&Wlds[0][0];
        #pragma unroll
        for (int i = 0; i < 4; ++i) Wl[t + i * TPB] = Wv[t + i * TPB];
    }
    const int g  = t & 15;
    const int sb = t >> 4;

    int   cidx[4][8];
    float wgt[4][8];
    #pragma unroll
    for (int i = 0; i < 4; ++i) {
        const int s = sb + 16 * i;
        int n = base + s;
        if (n >= N) n = N - 1;
        const int v = vidx[n];
        const int4 f0 = *(const int4*)&feats[(size_t)v * 8];
        const int4 f1 = *(const int4*)&feats[(size_t)v * 8 + 4];
        cidx[i][0] = f0.x; cidx[i][1] = f0.y; cidx[i][2] = f0.z; cidx[i][3] = f0.w;
        cidx[i][4] = f1.x; cidx[i][5] = f1.y; cidx[i][6] = f1.z; cidx[i][7] = f1.w;
        const float px = p[n * 3], py = p[n * 3 + 1], pz = p[n * 3 + 2];
        const float ox = 1.f - px, oy = 1.f - py, oz = 1.f - pz;
        wgt[i][0] = px * py * pz; wgt[i][1] = px * py * oz;
        wgt[i][2] = px * oy * pz; wgt[i][3] = ox * py * pz;
        wgt[i][4] = px * oy * oz; wgt[i][5] = ox * py * oz;
        wgt[i][6] = ox * oy * pz; wgt[i][7] = ox * oy * oz;
    }
    #pragma unroll
    for (int i = 0; i < 4; ++i) {
        float4 acc; acc.x = acc.y = acc.z = acc.w = 0.f;
        #pragma unroll
        for (int c = 0; c < 8; ++c) {
            const float4 val = *(const float4*)&values[(size_t)cidx[i][c] * 64 + 4 * g];
            const float w = wgt[i][c];
            acc.x = fmaf(w, val.x, acc.x); acc.y = fmaf(w, val.y, acc.y);
            acc.z = fmaf(w, val.z, acc.z); acc.w = fmaf(w, val.w, acc.w);
        }
        *(float4*)&featS[sb + 16 * i][4 * g] = acc;
    }
    __syncthreads();

    const int tx = t & 15, ty = t >> 4;
    float acc[4][4];
    {
        const float4 bb = ((const float4*)b)[tx];
        #pragma unroll
        for (int j = 0; j < 4; ++j) {
            acc[j][0] = bb.x; acc[j][1] = bb.y; acc[j][2] = bb.z; acc[j][3] = bb.w;
        }
    }
    #pragma unroll 4
    for (int d = 0; d < 64; ++d) {
        const float a0 = featS[4 * ty + 0][d];
        const float a1 = featS[4 * ty + 1][d];
        const float a2 = featS[4 * ty + 2][d];
        const float a3 = featS[4 * ty + 3][d];
        const float4 wr = *(const float4*)&Wlds[d][4 * tx];
        acc[0][0] = fmaf(a0, wr.x, acc[0][0]); acc[0][1] = fmaf(a0, wr.y, acc[0][1]);
        acc[0][2] = fmaf(a0, wr.z, acc[0][2]); acc[0][3] = fmaf(a0, wr.w, acc[0][3]);
        acc[1][0] = fmaf(a1, wr.x, acc[1][0]); acc[1][1] = fmaf(a1, wr.y, acc[1][1]);
        acc[1][2] = fmaf(a1, wr.z, acc[1][2]); acc[1][3] = fmaf(a1, wr.w, acc[1][3]);
        acc[2][0] = fmaf(a2, wr.x, acc[2][0]); acc[2][1] = fmaf(a2, wr.y, acc[2][1]);
        acc[2][2] = fmaf(a2, wr.z, acc[2][2]); acc[2][3] = fmaf(a2, wr.w, acc[2][3]);
        acc[3][0] = fmaf(a3, wr.x, acc[3][0]); acc[3][1] = fmaf(a3, wr.y, acc[3][1]);
        acc[3][2] = fmaf(a3, wr.z, acc[3][2]); acc[3][3] = fmaf(a3, wr.w, acc[3][3]);
    }
    #pragma unroll
    for (int j = 0; j < 4; ++j) {
        const int n = base + 4 * ty + j;
        if (n < N) {
            float4 o; o.x = acc[j][0]; o.y = acc[j][1]; o.z = acc[j][2]; o.w = acc[j][3];
            *(float4*)&out[(size_t)n * 64 + 4 * tx] = o;
        }
    }
}

extern "C" void kernel_launch(void* const* d_in, const int* in_sizes, int n_in,
                              void* d_out, int out_size, void* d_ws, size_t ws_size,
                              hipStream_t stream) {
    const float* values = (const float*)d_in[0];
    const float* p      = (const float*)d_in[1];
    const float* W      = (const float*)d_in[2];
    const float* b      = (const float*)d_in[3];
    const int*   feats  = (const int*)d_in[4];
    const int*   vidx   = (const int*)d_in[5];
    float* out = (float*)d_out;

    const int N  = in_sizes[5];
    const int KD = in_sizes[0];            // K * 64
    const int nblocks = (N + 63) / 64;

    const size_t val_bytes = (size_t)KD * 2;
    const size_t need      = val_bytes + 8192;
    if (ws_size >= need) {
        unsigned* valbf = (unsigned*)d_ws;
        uint4*    wfrag = (uint4*)((char*)d_ws + val_bytes);
        const int n8 = KD / 8;
        cvt_values_bf16<<<(n8 + TPB - 1) / TPB, TPB, 0, stream>>>(
            (const float4*)values, (uint4*)valbf, n8);
        cvt_w_frag<<<1, TPB, 0, stream>>>(W, wfrag);
        fused_embed_proj_mfma<<<nblocks, TPB, 0, stream>>>(
            valbf, p, wfrag, b, feats, vidx, out, N);
    } else {
        fused_embed_proj_fp32<<<nblocks, TPB, 0, stream>>>(
            values, p, W, b, feats, vidx, out, N);
    }
}

// Round 6
// 69.762 us; speedup vs baseline: 1.5579x; 1.0233x over previous
//
#include <hip/hip_runtime.h>

#define TPB 256

typedef __attribute__((ext_vector_type(8))) short bf16x8;
typedef __attribute__((ext_vector_type(4))) float f32x4;

__device__ __forceinline__ unsigned pack_bf16_rne(float lo, float hi) {
    union { float f; unsigned u; } a, b;
    a.f = lo; b.f = hi;
    unsigned ua = (a.u + 0x7fffu + ((a.u >> 16) & 1u)) >> 16;
    unsigned ub = (b.u + 0x7fffu + ((b.u >> 16) & 1u)) >> 16;
    return ua | (ub << 16);
}
__device__ __forceinline__ float bf_lo(unsigned u) {
    union { unsigned i; float f; } c; c.i = u << 16; return c.f;
}
__device__ __forceinline__ float bf_hi(unsigned u) {
    union { unsigned i; float f; } c; c.i = u & 0xffff0000u; return c.f;
}

// ---- merged conversion: values fp32 -> bf16 table, plus W -> MFMA B-frags ----
// blocks [0, nvb): values; block nvb: W fragments.
// W frag f = ct*2 + kf, lane l, elem j = W[kf*32 + 8*(l>>4) + j][ct*16 + (l&15)]
__global__ __launch_bounds__(TPB) void cvt_inputs(
    const float4* __restrict__ src, uint4* __restrict__ dst, int n8,
    const float* __restrict__ W, uint4* __restrict__ wfrag, int nvb)
{
    if ((int)blockIdx.x == nvb) {
        const int t = threadIdx.x;
        for (int e = t; e < 512; e += TPB) {
            const int l  = e & 63;
            const int f  = e >> 6;
            const int ct = f >> 1;
            const int kf = f & 1;
            const int col = ct * 16 + (l & 15);
            const int k0  = kf * 32 + 8 * (l >> 4);
            uint4 o;
            o.x = pack_bf16_rne(W[(k0 + 0) * 64 + col], W[(k0 + 1) * 64 + col]);
            o.y = pack_bf16_rne(W[(k0 + 2) * 64 + col], W[(k0 + 3) * 64 + col]);
            o.z = pack_bf16_rne(W[(k0 + 4) * 64 + col], W[(k0 + 5) * 64 + col]);
            o.w = pack_bf16_rne(W[(k0 + 6) * 64 + col], W[(k0 + 7) * 64 + col]);
            wfrag[e] = o;
        }
        return;
    }
    const int i = blockIdx.x * TPB + threadIdx.x;
    if (i < n8) {
        const float4 a = src[2 * i];
        const float4 b = src[2 * i + 1];
        uint4 o;
        o.x = pack_bf16_rne(a.x, a.y);
        o.y = pack_bf16_rne(a.z, a.w);
        o.z = pack_bf16_rne(b.x, b.y);
        o.w = pack_bf16_rne(b.z, b.w);
        dst[i] = o;
    }
}

// ---- main fused kernel: gather-direct-to-A-fragment, zero LDS, no barrier ----
// Block = 256 threads = 4 independent waves; wave w owns samples
// [blockIdx*64 + 16w, +16). Lane l gathers sample srow = l&15, dim octets
// o0 = l>>4 and o1 = 4 + (l>>4): the trilinear fp32 accumulator IS the MFMA
// A-fragment (A row = l&15, k = 8*(l>>4)+j per kf). Lanes sharing a sample
// (l, l+16, l+32, l+48) read adjacent 16B chunks of the same 128B value row
// -> fully coalesced. Projection = 8x mfma_f32_16x16x32_bf16 per wave.
__global__ __launch_bounds__(TPB) void fused_embed_proj_mfma(
    const unsigned* __restrict__ valbf,  // [K,32] packed bf16 rows (128 B/row)
    const float* __restrict__ p,         // [N,3]
    const uint4* __restrict__ wfrag,     // [8][64] B-fragments
    const float* __restrict__ b,         // [64]
    const int*   __restrict__ feats,     // [V,8]
    const int*   __restrict__ vidx,      // [N]
    float* __restrict__ out,             // [N,64]
    int N)
{
    const int t    = threadIdx.x;
    const int l    = t & 63;
    const int w    = t >> 6;
    const int base = blockIdx.x * 64 + 16 * w;   // this wave's 16-sample tile
    const int srow = l & 15;
    const int kq   = l >> 4;                     // k-octet 0..3

    int n = base + srow;
    if (n >= N) n = N - 1;                       // clamped lanes' rows never stored

    // ---- corner indices + trilinear weights (x4 redundant across k-groups) ----
    const int v = vidx[n];
    const int4 f0 = *(const int4*)&feats[(size_t)v * 8];
    const int4 f1 = *(const int4*)&feats[(size_t)v * 8 + 4];
    const int c0 = f0.x, c1 = f0.y, c2 = f0.z, c3 = f0.w;
    const int c4 = f1.x, c5 = f1.y, c6 = f1.z, c7 = f1.w;

    const float px = p[n * 3 + 0];
    const float py = p[n * 3 + 1];
    const float pz = p[n * 3 + 2];
    const float ox = 1.0f - px, oy = 1.0f - py, oz = 1.0f - pz;
    // corner order: [1,1,1],[1,1,0],[1,0,1],[0,1,1],[1,0,0],[0,1,0],[0,0,1],[0,0,0]
    float wgt[8];
    wgt[0] = px * py * pz;
    wgt[1] = px * py * oz;
    wgt[2] = px * oy * pz;
    wgt[3] = ox * py * pz;
    wgt[4] = px * oy * oz;
    wgt[5] = ox * py * oz;
    wgt[6] = ox * oy * pz;
    wgt[7] = ox * oy * oz;
    int cidx[8] = {c0, c1, c2, c3, c4, c5, c6, c7};

    // ---- 16 independent uint4 gathers -> fp32 A-fragment accumulators ----
    float a0[8] = {0.f,0.f,0.f,0.f,0.f,0.f,0.f,0.f};  // dims 8*kq .. 8*kq+7
    float a1[8] = {0.f,0.f,0.f,0.f,0.f,0.f,0.f,0.f};  // dims 32+8*kq .. +7
    #pragma unroll
    for (int c = 0; c < 8; ++c) {
        const unsigned* row = valbf + (size_t)cidx[c] * 32;
        const uint4 q0 = *(const uint4*)(row + 4 * kq);        // octet kq
        const uint4 q1 = *(const uint4*)(row + 16 + 4 * kq);   // octet kq+4
        const float wc = wgt[c];
        a0[0] = fmaf(wc, bf_lo(q0.x), a0[0]);
        a0[1] = fmaf(wc, bf_hi(q0.x), a0[1]);
        a0[2] = fmaf(wc, bf_lo(q0.y), a0[2]);
        a0[3] = fmaf(wc, bf_hi(q0.y), a0[3]);
        a0[4] = fmaf(wc, bf_lo(q0.z), a0[4]);
        a0[5] = fmaf(wc, bf_hi(q0.z), a0[5]);
        a0[6] = fmaf(wc, bf_lo(q0.w), a0[6]);
        a0[7] = fmaf(wc, bf_hi(q0.w), a0[7]);
        a1[0] = fmaf(wc, bf_lo(q1.x), a1[0]);
        a1[1] = fmaf(wc, bf_hi(q1.x), a1[1]);
        a1[2] = fmaf(wc, bf_lo(q1.y), a1[2]);
        a1[3] = fmaf(wc, bf_hi(q1.y), a1[3]);
        a1[4] = fmaf(wc, bf_lo(q1.z), a1[4]);
        a1[5] = fmaf(wc, bf_hi(q1.z), a1[5]);
        a1[6] = fmaf(wc, bf_lo(q1.w), a1[6]);
        a1[7] = fmaf(wc, bf_hi(q1.w), a1[7]);
    }

    // ---- pack accumulators into MFMA A-fragments ----
    bf16x8 afrag0, afrag1;
    {
        union { unsigned u[4]; bf16x8 v; } cv;
        cv.u[0] = pack_bf16_rne(a0[0], a0[1]);
        cv.u[1] = pack_bf16_rne(a0[2], a0[3]);
        cv.u[2] = pack_bf16_rne(a0[4], a0[5]);
        cv.u[3] = pack_bf16_rne(a0[6], a0[7]);
        afrag0 = cv.v;
        cv.u[0] = pack_bf16_rne(a1[0], a1[1]);
        cv.u[1] = pack_bf16_rne(a1[2], a1[3]);
        cv.u[2] = pack_bf16_rne(a1[4], a1[5]);
        cv.u[3] = pack_bf16_rne(a1[6], a1[7]);
        afrag1 = cv.v;
    }

    // ---- projection: 4 col-tiles x 2 MFMAs, W frags from L1 ----
    #pragma unroll
    for (int ct = 0; ct < 4; ++ct) {
        const float bias = b[ct * 16 + srow];
        f32x4 acc;
        acc[0] = bias; acc[1] = bias; acc[2] = bias; acc[3] = bias;
        union { uint4 u; bf16x8 v; } b0, b1;
        b0.u = wfrag[(ct * 2 + 0) * 64 + l];
        b1.u = wfrag[(ct * 2 + 1) * 64 + l];
        acc = __builtin_amdgcn_mfma_f32_16x16x32_bf16(afrag0, b0.v, acc, 0, 0, 0);
        acc = __builtin_amdgcn_mfma_f32_16x16x32_bf16(afrag1, b1.v, acc, 0, 0, 0);

        const int col = ct * 16 + srow;          // C col = lane&15
        #pragma unroll
        for (int r = 0; r < 4; ++r) {
            const int n2 = base + 4 * kq + r;    // C row = (lane>>4)*4 + r
            if (n2 < N)
                __builtin_nontemporal_store(acc[r], &out[(size_t)n2 * 64 + col]);
        }
    }
}

// ---- fallback: proven round-2 fp32 kernel (used only if ws too small) ----
__global__ __launch_bounds__(TPB) void fused_embed_proj_fp32(
    const float* __restrict__ values, const float* __restrict__ p,
    const float* __restrict__ W, const float* __restrict__ b,
    const int* __restrict__ feats, const int* __restrict__ vidx,
    float* __restrict__ out, int N)
{
    __shared__ float featS[64][68];
    __shared__ float Wlds[64][64];

    const int t    = threadIdx.x;
    const int base = blockIdx.x * 64;
    {
        const float4* Wv = (const float4*)W;
        float4*       Wl = (float4*)&Wlds[0][0];
        #pragma unroll
        for (int i = 0; i < 4; ++i) Wl[t + i * TPB] = Wv[t + i * TPB];
    }
    const int g  = t & 15;
    const int sb = t >> 4;

    int   cidx[4][8];
    float wgt[4][8];
    #pragma unroll
    for (int i = 0; i < 4; ++i) {
        const int s = sb + 16 * i;
        int n = base + s;
        if (n >= N) n = N - 1;
        const int v = vidx[n];
        const int4 f0 = *(const int4*)&feats[(size_t)v * 8];
        const int4 f1 = *(const int4*)&feats[(size_t)v * 8 + 4];
        cidx[i][0] = f0.x; cidx[i][1] = f0.y; cidx[i][2] = f0.z; cidx[i][3] = f0.w;
        cidx[i][4] = f1.x; cidx[i][5] = f1.y; cidx[i][6] = f1.z; cidx[i][7] = f1.w;
        const float px = p[n * 3], py = p[n * 3 + 1], pz = p[n * 3 + 2];
        const float ox = 1.f - px, oy = 1.f - py, oz = 1.f - pz;
        wgt[i][0] = px * py * pz; wgt[i][1] = px * py * oz;
        wgt[i][2] = px * oy * pz; wgt[i][3] = ox * py * pz;
        wgt[i][4] = px * oy * oz; wgt[i][5] = ox * py * oz;
        wgt[i][6] = ox * oy * pz; wgt[i][7] = ox * oy * oz;
    }
    #pragma unroll
    for (int i = 0; i < 4; ++i) {
        float4 acc; acc.x = acc.y = acc.z = acc.w = 0.f;
        #pragma unroll
        for (int c = 0; c < 8; ++c) {
            const float4 val = *(const float4*)&values[(size_t)cidx[i][c] * 64 + 4 * g];
            const float w = wgt[i][c];
            acc.x = fmaf(w, val.x, acc.x); acc.y = fmaf(w, val.y, acc.y);
            acc.z = fmaf(w, val.z, acc.z); acc.w = fmaf(w, val.w, acc.w);
        }
        *(float4*)&featS[sb + 16 * i][4 * g] = acc;
    }
    __syncthreads();

    const int tx = t & 15, ty = t >> 4;
    float acc[4][4];
    {
        const float4 bb = ((const float4*)b)[tx];
        #pragma unroll
        for (int j = 0; j < 4; ++j) {
            acc[j][0] = bb.x; acc[j][1] = bb.y; acc[j][2] = bb.z; acc[j][3] = bb.w;
        }
    }
    #pragma unroll 4
    for (int d = 0; d < 64; ++d) {
        const float a0 = featS[4 * ty + 0][d];
        const float a1 = featS[4 * ty + 1][d];
        const float a2 = featS[4 * ty + 2][d];
        const float a3 = featS[4 * ty + 3][d];
        const float4 wr = *(const float4*)&Wlds[d][4 * tx];
        acc[0][0] = fmaf(a0, wr.x, acc[0][0]); acc[0][1] = fmaf(a0, wr.y, acc[0][1]);
        acc[0][2] = fmaf(a0, wr.z, acc[0][2]); acc[0][3] = fmaf(a0, wr.w, acc[0][3]);
        acc[1][0] = fmaf(a1, wr.x, acc[1][0]); acc[1][1] = fmaf(a1, wr.y, acc[1][1]);
        acc[1][2] = fmaf(a1, wr.z, acc[1][2]); acc[1][3] = fmaf(a1, wr.w, acc[1][3]);
        acc[2][0] = fmaf(a2, wr.x, acc[2][0]); acc[2][1] = fmaf(a2, wr.y, acc[2][1]);
        acc[2][2] = fmaf(a2, wr.z, acc[2][2]); acc[2][3] = fmaf(a2, wr.w, acc[2][3]);
        acc[3][0] = fmaf(a3, wr.x, acc[3][0]); acc[3][1] = fmaf(a3, wr.y, acc[3][1]);
        acc[3][2] = fmaf(a3, wr.z, acc[3][2]); acc[3][3] = fmaf(a3, wr.w, acc[3][3]);
    }
    #pragma unroll
    for (int j = 0; j < 4; ++j) {
        const int n = base + 4 * ty + j;
        if (n < N) {
            float4 o; o.x = acc[j][0]; o.y = acc[j][1]; o.z = acc[j][2]; o.w = acc[j][3];
            *(float4*)&out[(size_t)n * 64 + 4 * tx] = o;
        }
    }
}

extern "C" void kernel_launch(void* const* d_in, const int* in_sizes, int n_in,
                              void* d_out, int out_size, void* d_ws, size_t ws_size,
                              hipStream_t stream) {
    const float* values = (const float*)d_in[0];
    const float* p      = (const float*)d_in[1];
    const float* W      = (const float*)d_in[2];
    const float* b      = (const float*)d_in[3];
    const int*   feats  = (const int*)d_in[4];
    const int*   vidx   = (const int*)d_in[5];
    float* out = (float*)d_out;

    const int N  = in_sizes[5];
    const int KD = in_sizes[0];            // K * 64
    const int nblocks = (N + 63) / 64;

    const size_t val_bytes = (size_t)KD * 2;
    const size_t need      = val_bytes + 8192;
    if (ws_size >= need) {
        unsigned* valbf = (unsigned*)d_ws;
        uint4*    wfrag = (uint4*)((char*)d_ws + val_bytes);
        const int n8  = KD / 8;
        const int nvb = (n8 + TPB - 1) / TPB;
        cvt_inputs<<<nvb + 1, TPB, 0, stream>>>(
            (const float4*)values, (uint4*)valbf, n8, W, wfrag, nvb);
        fused_embed_proj_mfma<<<nblocks, TPB, 0, stream>>>(
            valbf, p, wfrag, b, feats, vidx, out, N);
    } else {
        fused_embed_proj_fp32<<<nblocks, TPB, 0, stream>>>(
            values, p, W, b, feats, vidx, out, N);
    }
}

// Round 7
// 68.621 us; speedup vs baseline: 1.5838x; 1.0166x over previous
//
#include <hip/hip_runtime.h>

#define TPB 256

typedef __attribute__((ext_vector_type(8))) short bf16x8;
typedef __attribute__((ext_vector_type(4))) float f32x4;

__device__ __forceinline__ unsigned pack_bf16_rne(float lo, float hi) {
    union { float f; unsigned u; } a, b;
    a.f = lo; b.f = hi;
    unsigned ua = (a.u + 0x7fffu + ((a.u >> 16) & 1u)) >> 16;
    unsigned ub = (b.u + 0x7fffu + ((b.u >> 16) & 1u)) >> 16;
    return ua | (ub << 16);
}
__device__ __forceinline__ float bf_lo(unsigned u) {
    union { unsigned i; float f; } c; c.i = u << 16; return c.f;
}
__device__ __forceinline__ float bf_hi(unsigned u) {
    union { unsigned i; float f; } c; c.i = u & 0xffff0000u; return c.f;
}

// ---- merged conversion: values fp32 -> bf16 table, plus W -> MFMA B-frags ----
// blocks [0, nvb): values; block nvb: W fragments.
// W frag f = ct*2 + kf, lane l, elem j = W[kf*32 + 8*(l>>4) + j][ct*16 + (l&15)]
__global__ __launch_bounds__(TPB) void cvt_inputs(
    const float4* __restrict__ src, uint4* __restrict__ dst, int n8,
    const float* __restrict__ W, uint4* __restrict__ wfrag, int nvb)
{
    if ((int)blockIdx.x == nvb) {
        const int t = threadIdx.x;
        for (int e = t; e < 512; e += TPB) {
            const int l  = e & 63;
            const int f  = e >> 6;
            const int ct = f >> 1;
            const int kf = f & 1;
            const int col = ct * 16 + (l & 15);
            const int k0  = kf * 32 + 8 * (l >> 4);
            uint4 o;
            o.x = pack_bf16_rne(W[(k0 + 0) * 64 + col], W[(k0 + 1) * 64 + col]);
            o.y = pack_bf16_rne(W[(k0 + 2) * 64 + col], W[(k0 + 3) * 64 + col]);
            o.z = pack_bf16_rne(W[(k0 + 4) * 64 + col], W[(k0 + 5) * 64 + col]);
            o.w = pack_bf16_rne(W[(k0 + 6) * 64 + col], W[(k0 + 7) * 64 + col]);
            wfrag[e] = o;
        }
        return;
    }
    const int i = blockIdx.x * TPB + threadIdx.x;
    if (i < n8) {
        const float4 a = src[2 * i];
        const float4 b = src[2 * i + 1];
        uint4 o;
        o.x = pack_bf16_rne(a.x, a.y);
        o.y = pack_bf16_rne(a.z, a.w);
        o.z = pack_bf16_rne(b.x, b.y);
        o.w = pack_bf16_rne(b.z, b.w);
        dst[i] = o;
    }
}

// ---- main fused kernel: gather-direct-to-A-fragment, zero LDS, no barrier ----
// Block = 256 threads = 4 independent waves; wave w owns samples
// [blockIdx*64 + 16w, +16). Lane l gathers sample srow = l&15, dim octets
// kq = l>>4 and 4+kq: the trilinear fp32 accumulator IS the MFMA A-fragment.
// All 16 uint4 gathers are issued before any accumulation so they share one
// vmcnt window (needs the 256-VGPR budget from __launch_bounds__(256,2)).
__global__ __launch_bounds__(TPB, 2) void fused_embed_proj_mfma(
    const unsigned* __restrict__ valbf,  // [K,32] packed bf16 rows (128 B/row)
    const float* __restrict__ p,         // [N,3]
    const uint4* __restrict__ wfrag,     // [8][64] B-fragments
    const float* __restrict__ b,         // [64]
    const int*   __restrict__ feats,     // [V,8]
    const int*   __restrict__ vidx,      // [N]
    float* __restrict__ out,             // [N,64]
    int N)
{
    const int t    = threadIdx.x;
    const int l    = t & 63;
    const int w    = t >> 6;
    const int base = blockIdx.x * 64 + 16 * w;   // this wave's 16-sample tile
    const int srow = l & 15;
    const int kq   = l >> 4;                     // k-octet 0..3

    int n = base + srow;
    if (n >= N) n = N - 1;                       // clamped lanes' rows never stored

    // ---- corner indices + trilinear weights (x4 redundant across k-groups) ----
    const int v = vidx[n];
    const int4 f0 = *(const int4*)&feats[(size_t)v * 8];
    const int4 f1 = *(const int4*)&feats[(size_t)v * 8 + 4];

    const float px = p[n * 3 + 0];
    const float py = p[n * 3 + 1];
    const float pz = p[n * 3 + 2];
    const float ox = 1.0f - px, oy = 1.0f - py, oz = 1.0f - pz;
    // corner order: [1,1,1],[1,1,0],[1,0,1],[0,1,1],[1,0,0],[0,1,0],[0,0,1],[0,0,0]
    float wgt[8];
    wgt[0] = px * py * pz;
    wgt[1] = px * py * oz;
    wgt[2] = px * oy * pz;
    wgt[3] = ox * py * pz;
    wgt[4] = px * oy * oz;
    wgt[5] = ox * py * oz;
    wgt[6] = ox * oy * pz;
    wgt[7] = ox * oy * oz;
    const int cidx[8] = {f0.x, f0.y, f0.z, f0.w, f1.x, f1.y, f1.z, f1.w};

    // ---- issue ALL 16 gathers first (one vmcnt window, max MLP) ----
    uint4 q0s[8], q1s[8];
    #pragma unroll
    for (int c = 0; c < 8; ++c) {
        const unsigned* row = valbf + (size_t)cidx[c] * 32;
        q0s[c] = *(const uint4*)(row + 4 * kq);        // octet kq      (dims 8kq..)
        q1s[c] = *(const uint4*)(row + 16 + 4 * kq);   // octet kq+4    (dims 32+8kq..)
    }

    // ---- weighted accumulate -> fp32 A-fragment accumulators ----
    float a0[8] = {0.f,0.f,0.f,0.f,0.f,0.f,0.f,0.f};
    float a1[8] = {0.f,0.f,0.f,0.f,0.f,0.f,0.f,0.f};
    #pragma unroll
    for (int c = 0; c < 8; ++c) {
        const uint4 q0 = q0s[c];
        const uint4 q1 = q1s[c];
        const float wc = wgt[c];
        a0[0] = fmaf(wc, bf_lo(q0.x), a0[0]);
        a0[1] = fmaf(wc, bf_hi(q0.x), a0[1]);
        a0[2] = fmaf(wc, bf_lo(q0.y), a0[2]);
        a0[3] = fmaf(wc, bf_hi(q0.y), a0[3]);
        a0[4] = fmaf(wc, bf_lo(q0.z), a0[4]);
        a0[5] = fmaf(wc, bf_hi(q0.z), a0[5]);
        a0[6] = fmaf(wc, bf_lo(q0.w), a0[6]);
        a0[7] = fmaf(wc, bf_hi(q0.w), a0[7]);
        a1[0] = fmaf(wc, bf_lo(q1.x), a1[0]);
        a1[1] = fmaf(wc, bf_hi(q1.x), a1[1]);
        a1[2] = fmaf(wc, bf_lo(q1.y), a1[2]);
        a1[3] = fmaf(wc, bf_hi(q1.y), a1[3]);
        a1[4] = fmaf(wc, bf_lo(q1.z), a1[4]);
        a1[5] = fmaf(wc, bf_hi(q1.z), a1[5]);
        a1[6] = fmaf(wc, bf_lo(q1.w), a1[6]);
        a1[7] = fmaf(wc, bf_hi(q1.w), a1[7]);
    }

    // ---- pack accumulators into MFMA A-fragments ----
    bf16x8 afrag0, afrag1;
    {
        union { unsigned u[4]; bf16x8 v; } cv;
        cv.u[0] = pack_bf16_rne(a0[0], a0[1]);
        cv.u[1] = pack_bf16_rne(a0[2], a0[3]);
        cv.u[2] = pack_bf16_rne(a0[4], a0[5]);
        cv.u[3] = pack_bf16_rne(a0[6], a0[7]);
        afrag0 = cv.v;
        cv.u[0] = pack_bf16_rne(a1[0], a1[1]);
        cv.u[1] = pack_bf16_rne(a1[2], a1[3]);
        cv.u[2] = pack_bf16_rne(a1[4], a1[5]);
        cv.u[3] = pack_bf16_rne(a1[6], a1[7]);
        afrag1 = cv.v;
    }

    // ---- projection: 4 col-tiles x 2 MFMAs, W frags from L1 ----
    #pragma unroll
    for (int ct = 0; ct < 4; ++ct) {
        const float bias = b[ct * 16 + srow];
        f32x4 acc;
        acc[0] = bias; acc[1] = bias; acc[2] = bias; acc[3] = bias;
        union { uint4 u; bf16x8 v; } b0, b1;
        b0.u = wfrag[(ct * 2 + 0) * 64 + l];
        b1.u = wfrag[(ct * 2 + 1) * 64 + l];
        acc = __builtin_amdgcn_mfma_f32_16x16x32_bf16(afrag0, b0.v, acc, 0, 0, 0);
        acc = __builtin_amdgcn_mfma_f32_16x16x32_bf16(afrag1, b1.v, acc, 0, 0, 0);

        const int col = ct * 16 + srow;          // C col = lane&15
        #pragma unroll
        for (int r = 0; r < 4; ++r) {
            const int n2 = base + 4 * kq + r;    // C row = (lane>>4)*4 + r
            if (n2 < N)
                __builtin_nontemporal_store(acc[r], &out[(size_t)n2 * 64 + col]);
        }
    }
}

// ---- fallback: proven round-2 fp32 kernel (used only if ws too small) ----
__global__ __launch_bounds__(TPB) void fused_embed_proj_fp32(
    const float* __restrict__ values, const float* __restrict__ p,
    const float* __restrict__ W, const float* __restrict__ b,
    const int* __restrict__ feats, const int* __restrict__ vidx,
    float* __restrict__ out, int N)
{
    __shared__ float featS[64][68];
    __shared__ float Wlds[64][64];

    const int t    = threadIdx.x;
    const int base = blockIdx.x * 64;
    {
        const float4* Wv = (const float4*)W;
        float4*       Wl = (float4*)&Wlds[0][0];
        #pragma unroll
        for (int i = 0; i < 4; ++i) Wl[t + i * TPB] = Wv[t + i * TPB];
    }
    const int g  = t & 15;
    const int sb = t >> 4;

    int   cidx[4][8];
    float wgt[4][8];
    #pragma unroll
    for (int i = 0; i < 4; ++i) {
        const int s = sb + 16 * i;
        int n = base + s;
        if (n >= N) n = N - 1;
        const int v = vidx[n];
        const int4 f0 = *(const int4*)&feats[(size_t)v * 8];
        const int4 f1 = *(const int4*)&feats[(size_t)v * 8 + 4];
        cidx[i][0] = f0.x; cidx[i][1] = f0.y; cidx[i][2] = f0.z; cidx[i][3] = f0.w;
        cidx[i][4] = f1.x; cidx[i][5] = f1.y; cidx[i][6] = f1.z; cidx[i][7] = f1.w;
        const float px = p[n * 3], py = p[n * 3 + 1], pz = p[n * 3 + 2];
        const float ox = 1.f - px, oy = 1.f - py, oz = 1.f - pz;
        wgt[i][0] = px * py * pz; wgt[i][1] = px * py * oz;
        wgt[i][2] = px * oy * pz; wgt[i][3] = ox * py * pz;
        wgt[i][4] = px * oy * oz; wgt[i][5] = ox * py * oz;
        wgt[i][6] = ox * oy * pz; wgt[i][7] = ox * oy * oz;
    }
    #pragma unroll
    for (int i = 0; i < 4; ++i) {
        float4 acc; acc.x = acc.y = acc.z = acc.w = 0.f;
        #pragma unroll
        for (int c = 0; c < 8; ++c) {
            const float4 val = *(const float4*)&values[(size_t)cidx[i][c] * 64 + 4 * g];
            const float w = wgt[i][c];
            acc.x = fmaf(w, val.x, acc.x); acc.y = fmaf(w, val.y, acc.y);
            acc.z = fmaf(w, val.z, acc.z); acc.w = fmaf(w, val.w, acc.w);
        }
        *(float4*)&featS[sb + 16 * i][4 * g] = acc;
    }
    __syncthreads();

    const int tx = t & 15, ty = t >> 4;
    float acc[4][4];
    {
        const float4 bb = ((const float4*)b)[tx];
        #pragma unroll
        for (int j = 0; j < 4; ++j) {
            acc[j][0] = bb.x; acc[j][1] = bb.y; acc[j][2] = bb.z; acc[j][3] = bb.w;
        }
    }
    #pragma unroll 4
    for (int d = 0; d < 64; ++d) {
        const float a0 = featS[4 * ty + 0][d];
        const float a1 = featS[4 * ty + 1][d];
        const float a2 = featS[4 * ty + 2][d];
        const float a3 = featS[4 * ty + 3][d];
        const float4 wr = *(const float4*)&Wlds[d][4 * tx];
        acc[0][0] = fmaf(a0, wr.x, acc[0][0]); acc[0][1] = fmaf(a0, wr.y, acc[0][1]);
        acc[0][2] = fmaf(a0, wr.z, acc[0][2]); acc[0][3] = fmaf(a0, wr.w, acc[0][3]);
        acc[1][0] = fmaf(a1, wr.x, acc[1][0]); acc[1][1] = fmaf(a1, wr.y, acc[1][1]);
        acc[1][2] = fmaf(a1, wr.z, acc[1][2]); acc[1][3] = fmaf(a1, wr.w, acc[1][3]);
        acc[2][0] = fmaf(a2, wr.x, acc[2][0]); acc[2][1] = fmaf(a2, wr.y, acc[2][1]);
        acc[2][2] = fmaf(a2, wr.z, acc[2][2]); acc[2][3] = fmaf(a2, wr.w, acc[2][3]);
        acc[3][0] = fmaf(a3, wr.x, acc[3][0]); acc[3][1] = fmaf(a3, wr.y, acc[3][1]);
        acc[3][2] = fmaf(a3, wr.z, acc[3][2]); acc[3][3] = fmaf(a3, wr.w, acc[3][3]);
    }
    #pragma unroll
    for (int j = 0; j < 4; ++j) {
        const int n = base + 4 * ty + j;
        if (n < N) {
            float4 o; o.x = acc[j][0]; o.y = acc[j][1]; o.z = acc[j][2]; o.w = acc[j][3];
            *(float4*)&out[(size_t)n * 64 + 4 * tx] = o;
        }
    }
}

extern "C" void kernel_launch(void* const* d_in, const int* in_sizes, int n_in,
                              void* d_out, int out_size, void* d_ws, size_t ws_size,
                              hipStream_t stream) {
    const float* values = (const float*)d_in[0];
    const float* p      = (const float*)d_in[1];
    const float* W      = (const float*)d_in[2];
    const float* b      = (const float*)d_in[3];
    const int*   feats  = (const int*)d_in[4];
    const int*   vidx   = (const int*)d_in[5];
    float* out = (float*)d_out;

    const int N  = in_sizes[5];
    const int KD = in_sizes[0];            // K * 64
    const int nblocks = (N + 63) / 64;

    const size_t val_bytes = (size_t)KD * 2;
    const size_t need      = val_bytes + 8192;
    if (ws_size >= need) {
        unsigned* valbf = (unsigned*)d_ws;
        uint4*    wfrag = (uint4*)((char*)d_ws + val_bytes);
        const int n8  = KD / 8;
        const int nvb = (n8 + TPB - 1) / TPB;
        cvt_inputs<<<nvb + 1, TPB, 0, stream>>>(
            (const float4*)values, (uint4*)valbf, n8, W, wfrag, nvb);
        fused_embed_proj_mfma<<<nblocks, TPB, 0, stream>>>(
            valbf, p, wfrag, b, feats, vidx, out, N);
    } else {
        fused_embed_proj_fp32<<<nblocks, TPB, 0, stream>>>(
            values, p, W, b, feats, vidx, out, N);
    }
}